// Round 3
// baseline (889.306 us; speedup 1.0000x reference)
//
#include <hip/hip_runtime.h>

#define N 8192
#define K1 31   // K=30 -> k+1 = 31 neighbors kept per row/column

typedef unsigned int u32;

// monotone fp32-bits -> u32 key (larger float => larger key)
__device__ __forceinline__ u32 fkey(u32 u) {
    return (u & 0x80000000u) ? ~u : (u | 0x80000000u);
}

// ============================================================================
// Per-row select: 31st-largest key + tie cutoff index. One block per row.
//   t_out[row] = u32 key of the 31st largest value
//   L_out[row] = largest accepted index among ties:
//                membership(v at j) = key(v) > t || (key(v) == t && j <= L)
// 4-pass MSB radix-256 select over 32-bit keys staged in LDS.
// ============================================================================
__global__ __launch_bounds__(256) void row_select_kernel(
        const float* __restrict__ A, u32* __restrict__ t_out, int* __restrict__ L_out) {
    __shared__ u32 keys[N];            // 32 KB
    __shared__ u32 hist[4][256];       // per-wave histograms (atomic contention /4)
    __shared__ u32 scanb[256];
    __shared__ u32 sh_sel, sh_want, sh_gt, sh_ntie;
    __shared__ int tie[128];

    const int tid  = threadIdx.x;
    const int wave = tid >> 6;
    const int row  = blockIdx.x;

    // stage row as sortable keys (uint4 coalesced, 16B/lane)
    const uint4* A4 = (const uint4*)(A + (size_t)row * N);
#pragma unroll
    for (int it = 0; it < N / 4 / 256; ++it) {   // 8 iters
        uint4 v = A4[it * 256 + tid];
        int b = (it * 256 + tid) * 4;
        keys[b + 0] = fkey(v.x); keys[b + 1] = fkey(v.y);
        keys[b + 2] = fkey(v.z); keys[b + 3] = fkey(v.w);
    }
    if (tid == 0) { sh_sel = 0u; sh_want = K1; sh_gt = 0u; sh_ntie = 0u; }
    __syncthreads();

    for (int pass = 3; pass >= 0; --pass) {
        const u32 pref = sh_sel;         // stable: written before trailing barrier
        const u32 want = sh_want;
        hist[0][tid] = 0u; hist[1][tid] = 0u; hist[2][tid] = 0u; hist[3][tid] = 0u;
        __syncthreads();

        const u32 pmask = (pass == 3) ? 0u : (0xFFFFFFFFu << ((pass + 1) * 8));
        const int shift = pass * 8;
        for (int it = 0; it < N / 256; ++it) {
            u32 k = keys[it * 256 + tid];
            if ((k & pmask) == (pref & pmask))
                atomicAdd(&hist[wave][(k >> shift) & 0xFFu], 1u);
        }
        __syncthreads();

        scanb[tid] = hist[0][tid] + hist[1][tid] + hist[2][tid] + hist[3][tid];
        __syncthreads();
        // inclusive suffix sum (Hillis-Steele): scanb[t] = count of keys >= bin t
        for (int off = 1; off < 256; off <<= 1) {
            u32 add = (tid + off < 256) ? scanb[tid + off] : 0u;
            __syncthreads();
            scanb[tid] += add;
            __syncthreads();
        }
        u32 incl = scanb[tid];
        u32 abov = (tid < 255) ? scanb[tid + 1] : 0u;
        if (incl >= want && abov < want) {           // exactly one thread
            sh_sel  = pref | ((u32)tid << shift);
            sh_want = want - abov;
        }
        __syncthreads();
    }
    const u32 tkey = sh_sel;

    // count strictly-greater + collect tie indices
    u32 my_gt = 0;
    for (int it = 0; it < N / 256; ++it) {
        int j = it * 256 + tid;
        u32 k = keys[j];
        my_gt += (k > tkey) ? 1u : 0u;
        if (k == tkey) {
            u32 slot = atomicAdd(&sh_ntie, 1u);
            if (slot < 128u) tie[slot] = j;
        }
    }
    atomicAdd(&sh_gt, my_gt);
    __syncthreads();

    if (tid == 0) {
        int m  = K1 - (int)sh_gt;                    // ties to accept, in [1,31]
        int nt = (int)(sh_ntie < 128u ? sh_ntie : 128u);
        for (int a = 1; a < nt; ++a) {               // tiny insertion sort
            int v = tie[a], b = a - 1;
            while (b >= 0 && tie[b] > v) { tie[b + 1] = tie[b]; --b; }
            tie[b + 1] = v;
        }
        int L;
        if (m < 1) L = -1;
        else if (m <= nt) L = tie[m - 1];
        else L = 0x7FFFFFFF;                         // cap-overflow corner: accept all
        t_out[row] = tkey;
        L_out[row] = L;
    }
}

// ============================================================================
// 64x64 fp32 tile transpose, float4 global loads/stores, padded LDS.
// ============================================================================
__global__ __launch_bounds__(256) void transpose_kernel(
        const float* __restrict__ in, float* __restrict__ out) {
    __shared__ float tile[64][65];       // stride 65: column walks hit distinct banks
    const int tid = threadIdx.x;
    const int lx  = (tid & 15) * 4;      // float4 lane within 64-wide tile
    const int ly  = tid >> 4;            // 0..15
    const size_t x0 = (size_t)blockIdx.x * 64;
    const size_t y0 = (size_t)blockIdx.y * 64;

#pragma unroll
    for (int k = 0; k < 4; ++k) {
        int r = k * 16 + ly;
        float4 v = *(const float4*)(in + (y0 + r) * N + x0 + lx);
        tile[r][lx + 0] = v.x; tile[r][lx + 1] = v.y;
        tile[r][lx + 2] = v.z; tile[r][lx + 3] = v.w;
    }
    __syncthreads();
#pragma unroll
    for (int k = 0; k < 4; ++k) {
        int r = k * 16 + ly;             // transposed row = original col x0+r
        float4 o;
        o.x = tile[lx + 0][r]; o.y = tile[lx + 1][r];
        o.z = tile[lx + 2][r]; o.w = tile[lx + 3][r];
        *(float4*)(out + (x0 + r) * N + y0 + lx) = o;
    }
}

// ============================================================================
// Mask: out[i,j] = A[i,j] iff top31(row i) && top31(col j) && i != j.
// Bit-exact key compares; float4 per thread.
// ============================================================================
__global__ __launch_bounds__(256) void mask_kernel(
        const float* __restrict__ A,
        const u32* __restrict__ tk_r, const int* __restrict__ L_r,
        const u32* __restrict__ tk_c, const int* __restrict__ L_c,
        float* __restrict__ out) {
    const u32 gid = blockIdx.x * 256u + threadIdx.x;   // float4 units
    const int i  = (int)(gid >> 11);                   // 2048 float4 per row
    const int j0 = (int)(gid & 2047u) << 2;

    uint4 v = ((const uint4*)A)[gid];
    const u32 tr = tk_r[i];
    const int lr = L_r[i];
    uint4 tc = *(const uint4*)(tk_c + j0);
    int4  lc = *(const int4*)(L_c + j0);

    auto keep = [&](u32 bits, int j, u32 tcv, int lcv) -> u32 {
        u32 k = fkey(bits);
        bool rok = (k > tr)  || (k == tr  && j <= lr);
        bool cok = (k > tcv) || (k == tcv && i <= lcv);
        return (rok && cok && (i != j)) ? bits : 0u;
    };

    uint4 o;
    o.x = keep(v.x, j0 + 0, tc.x, lc.x);
    o.y = keep(v.y, j0 + 1, tc.y, lc.y);
    o.z = keep(v.z, j0 + 2, tc.z, lc.z);
    o.w = keep(v.w, j0 + 3, tc.w, lc.w);
    ((uint4*)out)[gid] = o;
}

// ============================================================================
extern "C" void kernel_launch(void* const* d_in, const int* in_sizes, int n_in,
                              void* d_out, int out_size, void* d_ws, size_t ws_size,
                              hipStream_t stream) {
    const float* A   = (const float*)d_in[0];
    float*       out = (float*)d_out;

    // ws: tk_r[N] u32 | L_r[N] i32 | tk_c[N] u32 | L_c[N] i32 = 128 KB
    u32* tk_r = (u32*)d_ws;
    int* L_r  = (int*)(tk_r + N);
    u32* tk_c = (u32*)(L_r + N);
    int* L_c  = (int*)(tk_c + N);

    // transpose scratch = d_out (256 MB), consumed before mask overwrites it
    float* T = out;

    row_select_kernel<<<dim3(N), dim3(256), 0, stream>>>(A, tk_r, L_r);
    transpose_kernel<<<dim3(N / 64, N / 64), dim3(256), 0, stream>>>(A, T);
    row_select_kernel<<<dim3(N), dim3(256), 0, stream>>>(T, tk_c, L_c);
    mask_kernel<<<dim3((u32)((size_t)N * N / 4 / 256)), dim3(256), 0, stream>>>(
        A, tk_r, L_r, tk_c, L_c, out);
}

// Round 4
// 676.763 us; speedup vs baseline: 1.3141x; 1.3141x over previous
//
#include <hip/hip_runtime.h>

#define N 8192
#define K1 31              // K=30 -> k+1 = 31 kept per row/column
#define CAP 1024           // candidate capacity per line (row or col)
#define NB 2048            // global histogram bins (top 11 key bits)
#define HSHIFT 21
#define TARGET 19200u      // sampled suffix target (~150 candidates/line expected)

typedef unsigned int u32;
typedef unsigned long long u64;

// monotone fp32-bits -> u32 key (larger float => larger key)
__device__ __forceinline__ u32 fkey(u32 u) {
    return (u & 0x80000000u) ? ~u : (u | 0x80000000u);
}
// pack (key, idx): larger u64 = larger key, or equal key and SMALLER idx
__device__ __forceinline__ u64 pack_ki(u32 key, u32 idx) {
    return ((u64)key << 32) | (u32)(~idx);
}

// ============================================================================
// 0) zero the global histogram + column counters (ws is re-poisoned per call)
// ============================================================================
__global__ __launch_bounds__(256) void init_kernel(u32* __restrict__ hist,
                                                   u32* __restrict__ colcnt) {
    int i = blockIdx.x * 256 + threadIdx.x;
    if (i < NB) hist[i] = 0u;
    for (int j = i; j < N; j += (int)gridDim.x * 256) colcnt[j] = 0u;
}

// ============================================================================
// 1) sampled global histogram: 1M samples (every 64th element), 2048 bins
// ============================================================================
__global__ __launch_bounds__(256) void sample_hist_kernel(const float* __restrict__ A,
                                                          u32* __restrict__ hist) {
    __shared__ u32 h[NB];
    const int tid = threadIdx.x;
    for (int b = tid; b < NB; b += 256) h[b] = 0u;
    __syncthreads();
    const size_t s0 = (size_t)blockIdx.x * 256 + tid;
#pragma unroll
    for (int k = 0; k < 16; ++k) {
        size_t s = s0 + (size_t)k * 65536;          // 256 blocks * 256 threads
        u32 bits = __float_as_uint(A[s * 64]);
        atomicAdd(&h[fkey(bits) >> HSHIFT], 1u);
    }
    __syncthreads();
    for (int b = tid; b < NB; b += 256)
        if (h[b]) atomicAdd(&hist[b], h[b]);
}

// ============================================================================
// 2) pick conservative global key threshold g: largest bin base with
//    sampled suffix count >= TARGET. One block.
// ============================================================================
__global__ __launch_bounds__(256) void pick_g_kernel(const u32* __restrict__ hist,
                                                     u32* __restrict__ g_out) {
    __shared__ u32 suf[NB + 1];
    __shared__ u32 part[256];
    const int tid = threadIdx.x;
    u32 loc[8];
    u32 s = 0;
    for (int k = 7; k >= 0; --k) { s += hist[tid * 8 + k]; loc[k] = s; }
    part[tid] = s;
    __syncthreads();
    for (int off = 1; off < 256; off <<= 1) {        // inclusive suffix scan
        u32 add = (tid + off < 256) ? part[tid + off] : 0u;
        __syncthreads();
        part[tid] += add;
        __syncthreads();
    }
    u32 higher = (tid < 255) ? part[tid + 1] : 0u;
    for (int k = 0; k < 8; ++k) suf[tid * 8 + k] = loc[k] + higher;
    if (tid == 0) suf[NB] = 0u;
    __syncthreads();
    for (int k = 0; k < 8; ++k) {
        int b = tid * 8 + k;
        if (suf[b] >= TARGET && suf[b + 1] < TARGET)   // exactly one b (suf monotone)
            *g_out = (u32)b << HSHIFT;
    }
}

// ============================================================================
// 3) streaming extraction: one block per row. Every element with key >= g is
//    appended to its row list (LDS, flushed coalesced) and its column list
//    (global atomic slot). Counts written for exactness checks.
// ============================================================================
__global__ __launch_bounds__(256) void extract_kernel(
        const float* __restrict__ A, const u32* __restrict__ g_ptr,
        u64* __restrict__ rowcand, u64* __restrict__ colcand,
        u32* __restrict__ rowcnt, u32* __restrict__ colcnt) {
    __shared__ u64 buf[CAP];
    __shared__ u32 rc;
    const int tid = threadIdx.x;
    const int row = blockIdx.x;
    if (tid == 0) rc = 0u;
    __syncthreads();
    const u32 g = *g_ptr;
    const uint4* A4 = (const uint4*)(A + (size_t)row * N);
#pragma unroll
    for (int it = 0; it < 8; ++it) {
        uint4 v = A4[it * 256 + tid];
        const int j = (it * 256 + tid) * 4;
        u32 ks[4] = { fkey(v.x), fkey(v.y), fkey(v.z), fkey(v.w) };
#pragma unroll
        for (int q = 0; q < 4; ++q) {
            if (ks[q] >= g) {
                const int c = j + q;
                u32 slot = atomicAdd(&rc, 1u);
                if (slot < CAP) buf[slot] = pack_ki(ks[q], (u32)c);
                u32 cs = atomicAdd(&colcnt[c], 1u);
                if (cs < CAP) colcand[(size_t)c * CAP + cs] = pack_ki(ks[q], (u32)row);
            }
        }
    }
    __syncthreads();
    u32 n = rc < CAP ? rc : CAP;
    for (u32 s = tid; s < n; s += 256) rowcand[(size_t)row * CAP + s] = buf[s];
    if (tid == 0) rowcnt[row] = rc;
}

// ============================================================================
// 4) exact select from candidates: 31st-largest (key,idx) via pairwise rank.
//    Flags lines needing the fallback (cnt<31 or overflow).
// ============================================================================
__global__ __launch_bounds__(256) void rank_select_kernel(
        const u64* __restrict__ cand, const u32* __restrict__ cnts,
        u32* __restrict__ t_out, int* __restrict__ L_out, u32* __restrict__ flag) {
    __shared__ u64 buf[CAP];
    const int line = blockIdx.x;
    const int tid  = threadIdx.x;
    const u32 cnt  = cnts[line];
    if (cnt < (u32)K1 || cnt > (u32)CAP) {
        if (tid == 0) flag[line] = 1u;
        return;
    }
    if (tid == 0) flag[line] = 0u;
    for (u32 s = tid; s < cnt; s += 256) buf[s] = cand[(size_t)line * CAP + s];
    __syncthreads();
    for (u32 s = tid; s < cnt; s += 256) {
        const u64 mine = buf[s];
        u32 r = 0;
        for (u32 q = 0; q < cnt; ++q) r += (buf[q] > mine) ? 1u : 0u;  // LDS broadcast
        if (r == (u32)(K1 - 1)) {
            t_out[line] = (u32)(mine >> 32);
            L_out[line] = (int)(~(u32)mine);
        }
    }
}

// ============================================================================
// 5) exact fallback (rare: early-exits on clear flag). Full LDS radix-256
//    select over 32-bit keys + binary-searched tie index L. Works for rows
//    (rstride=N, estride=1) and columns (rstride=1, estride=N).
// ============================================================================
__global__ __launch_bounds__(256) void fallback_select_kernel(
        const float* __restrict__ A, const u32* __restrict__ flag,
        long rstride, long estride, u32* __restrict__ t_out, int* __restrict__ L_out) {
    if (flag[blockIdx.x] == 0u) return;
    __shared__ u32 keys[N];            // 32 KB
    __shared__ u32 hist[4][256];
    __shared__ u32 scanb[256];
    __shared__ u32 sh_sel, sh_want, sh_gt, sh_cnt;

    const int tid  = threadIdx.x;
    const int wave = tid >> 6;
    const size_t base = (size_t)blockIdx.x * (size_t)rstride;

    for (int it = 0; it < N / 256; ++it) {
        int j = it * 256 + tid;
        keys[j] = fkey(__float_as_uint(A[base + (size_t)j * (size_t)estride]));
    }
    if (tid == 0) { sh_sel = 0u; sh_want = (u32)K1; sh_gt = 0u; }
    __syncthreads();

    for (int pass = 3; pass >= 0; --pass) {
        const u32 pref = sh_sel;
        const u32 want = sh_want;
        hist[0][tid] = 0u; hist[1][tid] = 0u; hist[2][tid] = 0u; hist[3][tid] = 0u;
        __syncthreads();
        const u32 pmask = (pass == 3) ? 0u : (0xFFFFFFFFu << ((pass + 1) * 8));
        const int shift = pass * 8;
        for (int it = 0; it < N / 256; ++it) {
            u32 k = keys[it * 256 + tid];
            if ((k & pmask) == (pref & pmask))
                atomicAdd(&hist[wave][(k >> shift) & 0xFFu], 1u);
        }
        __syncthreads();
        scanb[tid] = hist[0][tid] + hist[1][tid] + hist[2][tid] + hist[3][tid];
        __syncthreads();
        for (int off = 1; off < 256; off <<= 1) {
            u32 add = (tid + off < 256) ? scanb[tid + off] : 0u;
            __syncthreads();
            scanb[tid] += add;
            __syncthreads();
        }
        u32 incl = scanb[tid];
        u32 abov = (tid < 255) ? scanb[tid + 1] : 0u;
        if (incl >= want && abov < want) {
            sh_sel  = pref | ((u32)tid << shift);
            sh_want = want - abov;
        }
        __syncthreads();
    }
    const u32 tkey = sh_sel;

    u32 my = 0;
    for (int it = 0; it < N / 256; ++it) my += (keys[it * 256 + tid] > tkey) ? 1u : 0u;
    atomicAdd(&sh_gt, my);
    __syncthreads();
    const int m = K1 - (int)sh_gt;     // ties to accept, >= 1

    // binary search smallest X with #(ties at idx<=X) >= m  -> L = X
    int lo = 0, hi = N - 1;
    while (lo < hi) {
        int mid = (lo + hi) >> 1;
        if (tid == 0) sh_cnt = 0u;
        __syncthreads();
        u32 c = 0;
        for (int it = 0; it < N / 256; ++it) {
            int j = it * 256 + tid;
            c += (keys[j] == tkey && j <= mid) ? 1u : 0u;
        }
        atomicAdd(&sh_cnt, c);
        __syncthreads();
        if ((int)sh_cnt >= m) hi = mid; else lo = mid + 1;
        __syncthreads();               // protect sh_cnt reuse
    }
    if (tid == 0) { t_out[blockIdx.x] = tkey; L_out[blockIdx.x] = lo; }
}

// ============================================================================
// 6) mask: out[i,j] = A[i,j] iff top31(row i) && top31(col j) && i != j.
// ============================================================================
__global__ __launch_bounds__(256) void mask_kernel(
        const float* __restrict__ A,
        const u32* __restrict__ tk_r, const int* __restrict__ L_r,
        const u32* __restrict__ tk_c, const int* __restrict__ L_c,
        float* __restrict__ out) {
    const u32 gid = blockIdx.x * 256u + threadIdx.x;   // float4 units
    const int i  = (int)(gid >> 11);                   // 2048 float4 per row
    const int j0 = (int)(gid & 2047u) << 2;

    uint4 v = ((const uint4*)A)[gid];
    const u32 tr = tk_r[i];
    const int lr = L_r[i];
    uint4 tc = *(const uint4*)(tk_c + j0);
    int4  lc = *(const int4*)(L_c + j0);

    auto keep = [&](u32 bits, int j, u32 tcv, int lcv) -> u32 {
        u32 k = fkey(bits);
        bool rok = (k > tr)  || (k == tr  && j <= lr);
        bool cok = (k > tcv) || (k == tcv && i <= lcv);
        return (rok && cok && (i != j)) ? bits : 0u;
    };

    uint4 o;
    o.x = keep(v.x, j0 + 0, tc.x, lc.x);
    o.y = keep(v.y, j0 + 1, tc.y, lc.y);
    o.z = keep(v.z, j0 + 2, tc.z, lc.z);
    o.w = keep(v.w, j0 + 3, tc.w, lc.w);
    ((uint4*)out)[gid] = o;
}

// ============================================================================
extern "C" void kernel_launch(void* const* d_in, const int* in_sizes, int n_in,
                              void* d_out, int out_size, void* d_ws, size_t ws_size,
                              hipStream_t stream) {
    const float* A   = (const float*)d_in[0];
    float*       out = (float*)d_out;

    // ---- small arrays in ws (~300 KB) ----
    u32* hist   = (u32*)d_ws;            // NB
    u32* g_key  = hist + NB;             // 1 (+pad to 64)
    u32* rowcnt = g_key + 64;            // N
    u32* colcnt = rowcnt + N;            // N
    u32* rowflg = colcnt + N;            // N
    u32* colflg = rowflg + N;            // N
    u32* tk_r   = colflg + N;            // N
    int* L_r    = (int*)(tk_r + N);      // N
    u32* tk_c   = (u32*)(L_r + N);       // N
    int* L_c    = (int*)(tk_c + N);      // N

    // ---- candidate lists live in d_out (consumed before mask overwrites) ----
    u64* rowcand = (u64*)d_out;                          // N*CAP*8 = 64 MB
    u64* colcand = rowcand + (size_t)N * CAP;            // 64 MB

    init_kernel<<<dim3(32), dim3(256), 0, stream>>>(hist, colcnt);
    sample_hist_kernel<<<dim3(256), dim3(256), 0, stream>>>(A, hist);
    pick_g_kernel<<<dim3(1), dim3(256), 0, stream>>>(hist, g_key);
    extract_kernel<<<dim3(N), dim3(256), 0, stream>>>(A, g_key, rowcand, colcand,
                                                      rowcnt, colcnt);
    rank_select_kernel<<<dim3(N), dim3(256), 0, stream>>>(rowcand, rowcnt, tk_r, L_r, rowflg);
    rank_select_kernel<<<dim3(N), dim3(256), 0, stream>>>(colcand, colcnt, tk_c, L_c, colflg);
    fallback_select_kernel<<<dim3(N), dim3(256), 0, stream>>>(A, rowflg, (long)N, 1L, tk_r, L_r);
    fallback_select_kernel<<<dim3(N), dim3(256), 0, stream>>>(A, colflg, 1L, (long)N, tk_c, L_c);
    mask_kernel<<<dim3((u32)((size_t)N * N / 4 / 256)), dim3(256), 0, stream>>>(
        A, tk_r, L_r, tk_c, L_c, out);
}